// Round 4
// baseline (247.366 us; speedup 1.0000x reference)
//
#include <hip/hip_runtime.h>
#include <cstdint>
#include <cstddef>

#define LSEQ 1024
#define NH   16
#define NX   8
#define NACC 196   // 36 (G) + 128 (C) + 32 (trig moments)

// One 64-thread block per batch. Each lane accumulates 196 weight-independent
// moments over 16 rows; transpose-reduce via LDS; assemble 16x16 score from
// moments + weights; softmax; W_eff = Wo*attn*Wv; stream out = x*W_eff^T.
__global__ __launch_bounds__(64, 2)
void attn_moments(const float* __restrict__ x, const float* __restrict__ pos,
                  const float* __restrict__ Wq, const float* __restrict__ Wk,
                  const float* __restrict__ Wv, const float* __restrict__ Wo,
                  float* __restrict__ out) {
    // red: [64 values][65 stride] transpose-reduce buffer (stride 65 => both
    // write (lane-indexed) and read (row-indexed) sides are bank-conflict-free).
    __shared__ __align__(16) float red[64 * 65];   // 16640 B
    __shared__ float sums[256];                    // 196 used
    float* score_s = red;          // [256]  (aliased after reduce completes)
    float* attn_s  = red + 256;    // [256]
    float* M_s     = red + 512;    // [256]
    float* U_s     = red + 768;    // [128]  U = Wq*G
    float* weff_s  = red + 896;    // [128]

    const int lane = threadIdx.x;
    const int b    = blockIdx.x;
    const float* xb = x   + (size_t)b * LSEQ * NX;
    const float* pb = pos + (size_t)b * LSEQ;

    float A[NACC];
    #pragma unroll
    for (int i = 0; i < NACC; ++i) A[i] = 0.f;

    // ---------------- main loop: 16 rows per lane, 1-iter prefetch ----------
    float4 xa = *(const float4*)(xb + (size_t)lane * 8);
    float4 xc = *(const float4*)(xb + (size_t)lane * 8 + 4);
    float  pv = pb[lane];
    for (int i = 0; i < 16; ++i) {
        float4 nxa = xa, nxc = xc; float npv = pv;
        if (i < 15) {
            const int l = (i + 1) * 64 + lane;
            nxa = *(const float4*)(xb + (size_t)l * 8);
            nxc = *(const float4*)(xb + (size_t)l * 8 + 4);
            npv = pb[l];
        }
        const float px[8] = {xa.x, xa.y, xa.z, xa.w, xc.x, xc.y, xc.z, xc.w};

        // G (upper triangle incl. diagonal): 36 FMA
        {
            int idx = 0;
            #pragma unroll
            for (int p = 0; p < 8; ++p)
                #pragma unroll
                for (int q = p; q < 8; ++q) { A[idx] += px[p] * px[q]; ++idx; }
        }
        // harmonics sin/cos(m*pi*pos), m=1..16 via Chebyshev recurrence
        {
            const float s1 = sinpif(pv), c1 = cospif(pv);
            const float c1x2 = 2.f * c1;
            float s = s1, c = c1;        // m = 1
            float s_p = 0.f, c_p = 1.f;  // m = 0
            #pragma unroll
            for (int m = 1; m <= 16; ++m) {
                if (m > 1) {
                    const float s_n = c1x2 * s - s_p;
                    const float c_n = c1x2 * c - c_p;
                    s_p = s; c_p = c; s = s_n; c = c_n;
                }
                if (m <= 8) {
                    #pragma unroll
                    for (int ch = 0; ch < 8; ++ch) {
                        A[36 + ch * 16 + 2 * (m - 1)] += px[ch] * s;  // C[ch][sin_e]
                        A[36 + ch * 16 + 2 * m - 1]   += px[ch] * c;  // C[ch][cos_e]
                    }
                }
                A[163 + m] += s;   // sin moments -> A[164..179]
                A[179 + m] += c;   // cos moments -> A[180..195]
            }
        }
        xa = nxa; xc = nxc; pv = npv;
    }

    // ---------------- transpose-reduce 196 accums across 64 lanes -----------
    #pragma unroll
    for (int q = 0; q < 4; ++q) {
        #pragma unroll
        for (int v = 0; v < 64; ++v) {
            const int a = q * 64 + v;
            red[v * 65 + lane] = (a < NACC) ? A[a] : 0.f;
        }
        __syncthreads();
        float t = 0.f;
        const float* rp = red + lane * 65;
        #pragma unroll 8
        for (int r = 0; r < 64; ++r) t += rp[r];
        if (q * 64 + lane < 256) sums[q * 64 + lane] = t;
        __syncthreads();
    }

    // ---------------- score assembly --------------------------------------
    // G accessor: symmetric triangular index into sums[0..35]
    // U[d][y] = sum_x Wq[d,x] * G[x,y] : 2 entries per lane
    #pragma unroll
    for (int k = 0; k < 2; ++k) {
        const int u = lane * 2 + k;
        const int d = u >> 3, y = u & 7;
        float acc = 0.f;
        #pragma unroll
        for (int xx = 0; xx < 8; ++xx) {
            const int p = xx < y ? xx : y;
            const int q = xx < y ? y : xx;
            acc += Wq[d * 8 + xx] * sums[8 * p - (p * (p - 1)) / 2 + (q - p)];
        }
        U_s[u] = acc;
    }
    __syncthreads();

    const float* Cs = sums + 36;
    #pragma unroll
    for (int k = 0; k < 4; ++k) {
        const int idx = lane * 4 + k;
        const int d = idx >> 4, e = idx & 15;
        float a1 = 0.f, a2 = 0.f, a3 = 0.f;
        #pragma unroll
        for (int y = 0; y < 8; ++y) a1 += U_s[d * 8 + y] * Wk[e * 8 + y];
        #pragma unroll
        for (int xx = 0; xx < 8; ++xx) {
            a2 += Wq[d * 8 + xx] * Cs[xx * 16 + e];
            a3 += Wk[e * 8 + xx] * Cs[xx * 16 + d];
        }
        // D[d,e] from trig moments (product-to-sum)
        const int fi = (d >> 1) + 1, fj = (e >> 1) + 1;
        const int sp = fi + fj;
        const int sm = fi > fj ? fi - fj : fj - fi;
        const float Smp = sums[163 + sp];
        const float Cmp = sums[179 + sp];
        const float Sms = (sm == 0) ? 0.f : sums[163 + sm];
        const float Cms = (sm == 0) ? (float)LSEQ : sums[179 + sm];
        const bool de = !(d & 1), ee = !(e & 1);
        float Dv;
        if (de && ee)       Dv = 0.5f * (Cms - Cmp);                              // sin*sin
        else if (de && !ee) Dv = 0.5f * (Smp + (fi >= fj ? 1.f : -1.f) * Sms);    // sin*cos
        else if (!de && ee) Dv = 0.5f * (Smp + (fj >= fi ? 1.f : -1.f) * Sms);    // cos*sin
        else                Dv = 0.5f * (Cms + Cmp);                              // cos*cos
        score_s[idx] = (a1 + a2 + a3 + Dv) * 0.03125f;   // * 1/sqrt(1024)
    }
    __syncthreads();

    // ---------------- softmax over e (16 rows on 16 lanes) ------------------
    if (lane < 16) {
        float mx = -1e30f;
        #pragma unroll
        for (int e = 0; e < 16; ++e) mx = fmaxf(mx, score_s[lane * 16 + e]);
        float ex[16], sum = 0.f;
        #pragma unroll
        for (int e = 0; e < 16; ++e) { ex[e] = __expf(score_s[lane * 16 + e] - mx); sum += ex[e]; }
        const float inv = 1.f / sum;
        #pragma unroll
        for (int e = 0; e < 16; ++e) attn_s[lane * 16 + e] = ex[e] * inv;
    }
    __syncthreads();

    // M = Wo * attn : 4 entries per lane
    #pragma unroll
    for (int k = 0; k < 4; ++k) {
        const int idx = lane * 4 + k;
        const int h = idx >> 4, e = idx & 15;
        float acc = 0.f;
        #pragma unroll
        for (int d = 0; d < 16; ++d) acc += Wo[h * 16 + d] * attn_s[d * 16 + e];
        M_s[idx] = acc;
    }
    __syncthreads();

    // W_eff = M * Wv : 2 entries per lane
    #pragma unroll
    for (int k = 0; k < 2; ++k) {
        const int idx = lane * 2 + k;
        const int h = idx >> 3, xx = idx & 7;
        float acc = 0.f;
        #pragma unroll
        for (int e = 0; e < 16; ++e) acc += M_s[h * 16 + e] * Wv[e * 8 + xx];
        weff_s[idx] = acc;
    }
    __syncthreads();

    // ---------------- epilogue: out[l][h] = sum_x x[l][x] * W_eff[h][x] -----
    float Wr[128];
    #pragma unroll
    for (int k = 0; k < 32; ++k) {
        const float4 t4 = *(const float4*)(weff_s + k * 4);
        Wr[k * 4 + 0] = t4.x; Wr[k * 4 + 1] = t4.y; Wr[k * 4 + 2] = t4.z; Wr[k * 4 + 3] = t4.w;
    }
    for (int i = 0; i < 16; ++i) {
        const int l = i * 64 + lane;
        const float4 a = *(const float4*)(xb + (size_t)l * 8);
        const float4 c = *(const float4*)(xb + (size_t)l * 8 + 4);
        const float xr[8] = {a.x, a.y, a.z, a.w, c.x, c.y, c.z, c.w};
        float o[16];
        #pragma unroll
        for (int h = 0; h < 16; ++h) {
            float acc = 0.f;
            #pragma unroll
            for (int xx = 0; xx < 8; ++xx) acc += xr[xx] * Wr[h * 8 + xx];
            o[h] = acc;
        }
        const size_t base = ((size_t)b * LSEQ + l) * NH;
        #pragma unroll
        for (int g = 0; g < 4; ++g)
            *(float4*)(out + base + g * 4) = make_float4(o[g*4+0], o[g*4+1], o[g*4+2], o[g*4+3]);
    }
}

extern "C" void kernel_launch(void* const* d_in, const int* in_sizes, int n_in,
                              void* d_out, int out_size, void* d_ws, size_t ws_size,
                              hipStream_t stream) {
    const float* x   = (const float*)d_in[0];
    const float* pos = (const float*)d_in[1];
    const float* Wq  = (const float*)d_in[2];
    const float* Wk  = (const float*)d_in[3];
    const float* Wv  = (const float*)d_in[4];
    const float* Wo  = (const float*)d_in[5];
    float* out = (float*)d_out;
    const int B = in_sizes[1] / LSEQ;   // pos has B*L elements
    attn_moments<<<B, 64, 0, stream>>>(x, pos, Wq, Wk, Wv, Wo, out);
}